// Round 1
// baseline (403.964 us; speedup 1.0000x reference)
//
#include <hip/hip_runtime.h>
#include <hip/hip_bf16.h>
#include <stdint.h>
#include <stddef.h>

typedef unsigned short u16;
typedef __attribute__((ext_vector_type(8))) short short8;   // 8 x bf16 (4 VGPRs) MFMA A/B frag
typedef __attribute__((ext_vector_type(4))) float f32x4;    // MFMA C/D frag
typedef __attribute__((ext_vector_type(4))) float f4;

constexpr int B_ = 2, S_ = 2048, D_ = 1024, H_ = 16;
constexpr size_t OUT_ELEMS = (size_t)B_ * S_ * D_;          // 4,194,304

__device__ __forceinline__ u16 f2bf(float f) {              // RNE f32 -> bf16
    union { float f; unsigned u; } v; v.f = f;
    unsigned r = 0x7FFFu + ((v.u >> 16) & 1u);
    return (u16)((v.u + r) >> 16);
}

// ---------------------------------------------------------------------------
// Weight cast+transpose: W [1024,1024] f32 -> Wt [N][K] bf16 (4 matrices, z)
// ---------------------------------------------------------------------------
__global__ __launch_bounds__(256) void wtrans_kernel(
    const float* __restrict__ W0, const float* __restrict__ W1,
    const float* __restrict__ W2, const float* __restrict__ W3,
    u16* __restrict__ T0, u16* __restrict__ T1, u16* __restrict__ T2, u16* __restrict__ T3)
{
    __shared__ __align__(16) u16 Ts[64][72];                 // +8 pad breaks bank conflicts
    const float* W = blockIdx.z == 0 ? W0 : blockIdx.z == 1 ? W1 : blockIdx.z == 2 ? W2 : W3;
    u16*         T = blockIdx.z == 0 ? T0 : blockIdx.z == 1 ? T1 : blockIdx.z == 2 ? T2 : T3;
    const int t = threadIdx.x;
    const int r0 = blockIdx.y * 64, c0 = blockIdx.x * 64;
    const int row = t >> 2, qd = t & 3;

    const float* src = W + (size_t)(r0 + row) * 1024 + c0 + qd * 16;
    u16 tmp[16];
    #pragma unroll
    for (int j = 0; j < 16; j += 4) {
        f4 v = *(const f4*)(src + j);
        tmp[j] = f2bf(v[0]); tmp[j+1] = f2bf(v[1]); tmp[j+2] = f2bf(v[2]); tmp[j+3] = f2bf(v[3]);
    }
    #pragma unroll
    for (int j = 0; j < 16; j++) Ts[row][qd * 16 + j] = tmp[j];
    __syncthreads();
    short8 o0, o1;
    #pragma unroll
    for (int j = 0; j < 8; j++) { o0[j] = (short)Ts[qd*16 + j][row]; o1[j] = (short)Ts[qd*16 + 8 + j][row]; }
    u16* dst = T + (size_t)(c0 + row) * 1024 + r0 + qd * 16;
    *(short8*)dst = o0;
    *(short8*)(dst + 8) = o1;
}

// ---------------------------------------------------------------------------
// Per-head V transpose: vp [B,S,D] bf16 -> vt [B*H][64][S] bf16
// ---------------------------------------------------------------------------
__global__ __launch_bounds__(256) void vtrans_kernel(const u16* __restrict__ vp, u16* __restrict__ vt)
{
    __shared__ __align__(16) u16 Vs[64][72];
    const int t = threadIdx.x;
    const int s0 = blockIdx.x * 64;
    const int bh = blockIdx.y, b = bh >> 4, h = bh & 15;
    #pragma unroll
    for (int i = 0; i < 2; i++) {
        int c = t + 256 * i, row = c >> 3, ch = c & 7;
        *(short8*)(&Vs[row][ch * 8]) =
            *(const short8*)(vp + ((size_t)b * S_ + s0 + row) * D_ + h * 64 + ch * 8);
    }
    __syncthreads();
    #pragma unroll
    for (int i = 0; i < 2; i++) {
        int c = t + 256 * i, d = c >> 3, ch = c & 7;
        short8 o;
        #pragma unroll
        for (int j = 0; j < 8; j++) o[j] = (short)Vs[ch * 8 + j][d];
        *(short8*)(vt + ((size_t)bh * 64 + d) * S_ + s0 + ch * 8) = o;
    }
}

// ---------------------------------------------------------------------------
// GEMM: C[M,N] = (A[M,K] @ Bt[N,K]^T + bias) * scale.  128x128 tile, BK=32,
// 4 waves, 4x4 frags of mfma_f32_16x16x32_bf16, reg-staged swizzled LDS.
// ---------------------------------------------------------------------------
struct Stage { short8 h[2]; };

template<int A_IS_F32>
__device__ __forceinline__ void stage_load(Stage& st, const void* Aptr, int row0, int K, int k0, int t) {
    if constexpr (A_IS_F32) {
        const float* Af = (const float*)Aptr;
        const int row = t >> 1, half = t & 1;
        const float* p = Af + (size_t)(row0 + row) * K + k0 + half * 16;
        #pragma unroll
        for (int j = 0; j < 2; j++) {
            f4 v0 = *(const f4*)(p + j * 8);
            f4 v1 = *(const f4*)(p + j * 8 + 4);
            short8 hh;
            hh[0]=(short)f2bf(v0[0]); hh[1]=(short)f2bf(v0[1]); hh[2]=(short)f2bf(v0[2]); hh[3]=(short)f2bf(v0[3]);
            hh[4]=(short)f2bf(v1[0]); hh[5]=(short)f2bf(v1[1]); hh[6]=(short)f2bf(v1[2]); hh[7]=(short)f2bf(v1[3]);
            st.h[j] = hh;
        }
    } else {
        const u16* Ah = (const u16*)Aptr;
        #pragma unroll
        for (int j = 0; j < 2; j++) {
            int c = 2 * t + j, row = c >> 2, ch = c & 3;
            st.h[j] = *(const short8*)(Ah + (size_t)(row0 + row) * K + k0 + ch * 8);
        }
    }
}

template<int A_IS_F32>
__device__ __forceinline__ void stage_store(const Stage& st, u16* Ls, int t) {
    if constexpr (A_IS_F32) {
        const int row = t >> 1, half = t & 1;
        #pragma unroll
        for (int j = 0; j < 2; j++) {
            int byteo = half * 32 + j * 16;
            *(short8*)((char*)Ls + row * 64 + (byteo ^ ((row & 3) << 4))) = st.h[j];
        }
    } else {
        #pragma unroll
        for (int j = 0; j < 2; j++) {
            int c = 2 * t + j, row = c >> 2, ch = c & 3;
            *(short8*)((char*)Ls + row * 64 + ((ch * 16) ^ ((row & 3) << 4))) = st.h[j];
        }
    }
}

template<int A_IS_F32, int OUT_IS_F32>
__global__ __launch_bounds__(256, 2)
void gemm_bt(const void* __restrict__ Aptr, const u16* __restrict__ Bt,
             const float* __restrict__ bias, void* __restrict__ Cptr,
             int M, int N, int K, float scale)
{
    __shared__ __align__(16) u16 As[128 * 32];
    __shared__ __align__(16) u16 Bs[128 * 32];

    const int t = threadIdx.x;
    const int w = t >> 6, l = t & 63, lr = l >> 4, lc = l & 15;
    const int wr = w >> 1, wc = w & 1;
    const int row0 = blockIdx.y * 128, col0 = blockIdx.x * 128;

    f32x4 acc[4][4] = {};
    Stage sa, sb;
    stage_load<A_IS_F32>(sa, Aptr, row0, K, 0, t);
    stage_load<0>(sb, (const void*)Bt, col0, K, 0, t);

    for (int k0 = 0; k0 < K; k0 += 32) {
        __syncthreads();
        stage_store<A_IS_F32>(sa, As, t);
        stage_store<0>(sb, Bs, t);
        __syncthreads();
        const int kn = (k0 + 32 < K) ? (k0 + 32) : 0;   // last-iter dummy prefetch of tile 0
        stage_load<A_IS_F32>(sa, Aptr, row0, K, kn, t);
        stage_load<0>(sb, (const void*)Bt, col0, K, kn, t);

        short8 af[4], bf_[4];
        #pragma unroll
        for (int mm = 0; mm < 4; mm++) {
            int r = wr * 64 + mm * 16 + lc;
            af[mm] = *(const short8*)((const char*)As + r * 64 + ((lr * 16) ^ ((r & 3) << 4)));
        }
        #pragma unroll
        for (int nn = 0; nn < 4; nn++) {
            int r = wc * 64 + nn * 16 + lc;
            bf_[nn] = *(const short8*)((const char*)Bs + r * 64 + ((lr * 16) ^ ((r & 3) << 4)));
        }
        #pragma unroll
        for (int mm = 0; mm < 4; mm++)
            #pragma unroll
            for (int nn = 0; nn < 4; nn++)
                acc[mm][nn] = __builtin_amdgcn_mfma_f32_16x16x32_bf16(af[mm], bf_[nn], acc[mm][nn], 0, 0, 0);
    }

    float bv[4];
    #pragma unroll
    for (int nn = 0; nn < 4; nn++) bv[nn] = bias[col0 + wc * 64 + nn * 16 + lc];

    #pragma unroll
    for (int mm = 0; mm < 4; mm++) {
        const int row = row0 + wr * 64 + mm * 16 + lr * 4;
        #pragma unroll
        for (int nn = 0; nn < 4; nn++) {
            const int col = col0 + wc * 64 + nn * 16 + lc;
            #pragma unroll
            for (int r = 0; r < 4; r++) {
                float vv = (acc[mm][nn][r] + bv[nn]) * scale;
                if constexpr (OUT_IS_F32) ((float*)Cptr)[(size_t)(row + r) * N + col] = vv;
                else                      ((u16*) Cptr)[(size_t)(row + r) * N + col] = f2bf(vv);
            }
        }
    }
}

// ---------------------------------------------------------------------------
// Fused attention. Block = (64 q-rows) x (one b,h). 4 waves x 16 rows each.
// Two passes over 128-wide K-tiles: pass1 = online max/sum, pass2 = P write
// (f32, normalized) + PV accumulate via per-wave LDS P buffer.
// qp is pre-scaled by 1/8, so scores come out of MFMA already scaled.
// ---------------------------------------------------------------------------
__global__ __launch_bounds__(256, 2)
void attn_kernel(const u16* __restrict__ qp, const u16* __restrict__ kp,
                 const u16* __restrict__ vt, float* __restrict__ Pout,
                 u16* __restrict__ xout)
{
    __shared__ __align__(16) u16 Qs[64 * 64];     //  8KB, 128B rows, swizzled
    __shared__ __align__(16) u16 Ks[128 * 64];    // 16KB, 128B rows, swizzled
    __shared__ __align__(16) u16 Vts[64 * 128];   // 16KB, 256B rows, swizzled
    __shared__ __align__(16) u16 Ps[4 * 16 * 136];// 17KB, per-wave P, +8 pad

    const int t = threadIdx.x;
    const int w = t >> 6, l = t & 63, lr = l >> 4, lc = l & 15;
    const int q0 = blockIdx.x * 64;
    const int bh = blockIdx.y, b = bh >> 4, h = bh & 15;
    const float L2E = 1.4426950408889634f;

    // stage Q tile [64][64]
    #pragma unroll
    for (int i = 0; i < 2; i++) {
        int c = t + 256 * i, row = c >> 3, ch = c & 7;
        short8 vq = *(const short8*)(qp + ((size_t)b * S_ + q0 + row) * D_ + h * 64 + ch * 8);
        *(short8*)((char*)Qs + row * 128 + ((ch * 16) ^ ((row & 7) << 4))) = vq;
    }
    __syncthreads();

    short8 qf[2];
    {
        int r = w * 16 + lc;
        const char* qb = (const char*)Qs + r * 128;
        int sw = (r & 7) << 4;
        qf[0] = *(const short8*)(qb + ((lr * 16) ^ sw));
        qf[1] = *(const short8*)(qb + ((64 + lr * 16) ^ sw));
    }

    float m_[4], sum_[4];
    #pragma unroll
    for (int r = 0; r < 4; r++) { m_[r] = -1e30f; sum_[r] = 0.f; }

    // ------------------ pass 1: row max + sum ------------------
    for (int kt = 0; kt < 16; kt++) {
        short8 kv[4];
        #pragma unroll
        for (int i = 0; i < 4; i++) {
            int c = t + 256 * i, row = c >> 3, ch = c & 7;
            kv[i] = *(const short8*)(kp + ((size_t)b * S_ + kt * 128 + row) * D_ + h * 64 + ch * 8);
        }
        __syncthreads();
        #pragma unroll
        for (int i = 0; i < 4; i++) {
            int c = t + 256 * i, row = c >> 3, ch = c & 7;
            *(short8*)((char*)Ks + row * 128 + ((ch * 16) ^ ((row & 7) << 4))) = kv[i];
        }
        __syncthreads();

        f32x4 sacc[8] = {};
        #pragma unroll
        for (int f = 0; f < 8; f++) {
            int r = f * 16 + lc;
            const char* kb = (const char*)Ks + r * 128;
            int sw = (r & 7) << 4;
            short8 b0 = *(const short8*)(kb + ((lr * 16) ^ sw));
            short8 b1 = *(const short8*)(kb + ((64 + lr * 16) ^ sw));
            sacc[f] = __builtin_amdgcn_mfma_f32_16x16x32_bf16(qf[0], b0, sacc[f], 0, 0, 0);
            sacc[f] = __builtin_amdgcn_mfma_f32_16x16x32_bf16(qf[1], b1, sacc[f], 0, 0, 0);
        }

        float tm[4];
        #pragma unroll
        for (int r = 0; r < 4; r++) tm[r] = -1e30f;
        #pragma unroll
        for (int f = 0; f < 8; f++)
            #pragma unroll
            for (int r = 0; r < 4; r++) tm[r] = fmaxf(tm[r], sacc[f][r]);
        #pragma unroll
        for (int o = 1; o < 16; o <<= 1)
            #pragma unroll
            for (int r = 0; r < 4; r++) tm[r] = fmaxf(tm[r], __shfl_xor(tm[r], o));

        float nm[4], ts[4];
        #pragma unroll
        for (int r = 0; r < 4; r++) { nm[r] = fmaxf(m_[r], tm[r]); ts[r] = 0.f; }
        #pragma unroll
        for (int f = 0; f < 8; f++)
            #pragma unroll
            for (int r = 0; r < 4; r++) ts[r] += exp2f((sacc[f][r] - nm[r]) * L2E);
        #pragma unroll
        for (int o = 1; o < 16; o <<= 1)
            #pragma unroll
            for (int r = 0; r < 4; r++) ts[r] += __shfl_xor(ts[r], o);
        #pragma unroll
        for (int r = 0; r < 4; r++) {
            sum_[r] = sum_[r] * exp2f((m_[r] - nm[r]) * L2E) + ts[r];
            m_[r] = nm[r];
        }
    }

    float inv_[4];
    #pragma unroll
    for (int r = 0; r < 4; r++) inv_[r] = 1.0f / sum_[r];

    // ------------------ pass 2: write P, accumulate PV ------------------
    f32x4 xacc[4] = {};
    for (int kt = 0; kt < 16; kt++) {
        short8 kv[4], vv[4];
        #pragma unroll
        for (int i = 0; i < 4; i++) {
            int c = t + 256 * i, row = c >> 3, ch = c & 7;
            kv[i] = *(const short8*)(kp + ((size_t)b * S_ + kt * 128 + row) * D_ + h * 64 + ch * 8);
        }
        #pragma unroll
        for (int i = 0; i < 4; i++) {
            int c = t + 256 * i, row = c >> 4, ch = c & 15;
            vv[i] = *(const short8*)(vt + ((size_t)bh * 64 + row) * S_ + kt * 128 + ch * 8);
        }
        __syncthreads();
        #pragma unroll
        for (int i = 0; i < 4; i++) {
            int c = t + 256 * i, row = c >> 3, ch = c & 7;
            *(short8*)((char*)Ks + row * 128 + ((ch * 16) ^ ((row & 7) << 4))) = kv[i];
        }
        #pragma unroll
        for (int i = 0; i < 4; i++) {
            int c = t + 256 * i, row = c >> 4, ch = c & 15;
            *(short8*)((char*)Vts + row * 256 + ((ch * 16) ^ ((row & 7) << 4))) = vv[i];
        }
        __syncthreads();

        f32x4 sacc[8] = {};
        #pragma unroll
        for (int f = 0; f < 8; f++) {
            int r = f * 16 + lc;
            const char* kb = (const char*)Ks + r * 128;
            int sw = (r & 7) << 4;
            short8 b0 = *(const short8*)(kb + ((lr * 16) ^ sw));
            short8 b1 = *(const short8*)(kb + ((64 + lr * 16) ^ sw));
            sacc[f] = __builtin_amdgcn_mfma_f32_16x16x32_bf16(qf[0], b0, sacc[f], 0, 0, 0);
            sacc[f] = __builtin_amdgcn_mfma_f32_16x16x32_bf16(qf[1], b1, sacc[f], 0, 0, 0);
        }

        const size_t prow = (size_t)bh * S_ + q0 + w * 16 + lr * 4;
        #pragma unroll
        for (int f = 0; f < 8; f++) {
            #pragma unroll
            for (int r = 0; r < 4; r++) {
                float p = exp2f((sacc[f][r] - m_[r]) * L2E) * inv_[r];
                Pout[(prow + r) * S_ + kt * 128 + f * 16 + lc] = p;
                Ps[w * 2176 + (lr * 4 + r) * 136 + f * 16 + lc] = f2bf(p);
            }
        }

        #pragma unroll
        for (int kk = 0; kk < 4; kk++) {
            short8 pa = *(const short8*)((const char*)Ps + w * 4352 + lc * 272 + kk * 64 + lr * 16);
            #pragma unroll
            for (int n = 0; n < 4; n++) {
                int rr = n * 16 + lc;
                short8 vb = *(const short8*)((const char*)Vts + rr * 256 + ((kk * 64 + lr * 16) ^ ((rr & 7) << 4)));
                xacc[n] = __builtin_amdgcn_mfma_f32_16x16x32_bf16(pa, vb, xacc[n], 0, 0, 0);
            }
        }
    }

    #pragma unroll
    for (int n = 0; n < 4; n++) {
        #pragma unroll
        for (int r = 0; r < 4; r++) {
            int row = q0 + w * 16 + lr * 4 + r;
            int col = h * 64 + n * 16 + lc;
            xout[((size_t)b * S_ + row) * D_ + col] = f2bf(xacc[n][r]);
        }
    }
}

// ---------------------------------------------------------------------------
extern "C" void kernel_launch(void* const* d_in, const int* in_sizes, int n_in,
                              void* d_out, int out_size, void* d_ws, size_t ws_size,
                              hipStream_t stream)
{
    const float* qin = (const float*)d_in[0];
    const float* kin = (const float*)d_in[1];
    const float* vin = (const float*)d_in[2];
    const float* Wq  = (const float*)d_in[3];
    const float* bq  = (const float*)d_in[4];
    const float* Wk  = (const float*)d_in[5];
    const float* bk  = (const float*)d_in[6];
    const float* Wv  = (const float*)d_in[7];
    const float* bv  = (const float*)d_in[8];
    const float* Wo  = (const float*)d_in[9];
    const float* bo  = (const float*)d_in[10];

    // ws layout (u16 elements): 4x Wt (1M each) | qp | kp | vp (4M each) | vt | x
    u16* base = (u16*)d_ws;
    u16* Wqt = base;
    u16* Wkt = base + 1048576;
    u16* Wvt = base + 2097152;
    u16* Wot = base + 3145728;
    u16* qpb = base + 4194304;
    u16* kpb = base + 8388608;
    u16* vpb = base + 12582912;
    u16* vtb = base + 16777216;
    u16* xb  = base + 20971520;   // total 48MB

    float* out  = (float*)d_out;
    float* Pout = out + OUT_ELEMS;

    const int M = B_ * S_;  // 4096

    wtrans_kernel<<<dim3(16, 16, 4), 256, 0, stream>>>(Wq, Wk, Wv, Wo, Wqt, Wkt, Wvt, Wot);
    // qp scaled by 1/sqrt(DK) = 0.125 (exact power of two)
    gemm_bt<1, 0><<<dim3(8, 32), 256, 0, stream>>>(qin, Wqt, bq, qpb, M, D_, D_, 0.125f);
    gemm_bt<1, 0><<<dim3(8, 32), 256, 0, stream>>>(kin, Wkt, bk, kpb, M, D_, D_, 1.0f);
    gemm_bt<1, 0><<<dim3(8, 32), 256, 0, stream>>>(vin, Wvt, bv, vpb, M, D_, D_, 1.0f);
    vtrans_kernel<<<dim3(32, 32), 256, 0, stream>>>(vpb, vtb);
    attn_kernel<<<dim3(32, 32), 256, 0, stream>>>(qpb, kpb, vtb, Pout, xb);
    gemm_bt<0, 1><<<dim3(8, 32), 256, 0, stream>>>(xb, Wot, bo, out, M, D_, D_, 1.0f);
}

// Round 2
// 328.072 us; speedup vs baseline: 1.2313x; 1.2313x over previous
//
#include <hip/hip_runtime.h>
#include <hip/hip_bf16.h>
#include <stdint.h>
#include <stddef.h>

typedef unsigned short u16;
typedef __attribute__((ext_vector_type(8))) short short8;   // 8 x bf16 (4 VGPRs) MFMA A/B frag
typedef __attribute__((ext_vector_type(4))) float f32x4;    // MFMA C/D frag
typedef __attribute__((ext_vector_type(4))) float f4;

constexpr int B_ = 2, S_ = 2048, D_ = 1024, H_ = 16;
constexpr size_t OUT_ELEMS = (size_t)B_ * S_ * D_;          // 4,194,304

__device__ __forceinline__ u16 f2bf(float f) {              // RNE f32 -> bf16
    union { float f; unsigned u; } v; v.f = f;
    unsigned r = 0x7FFFu + ((v.u >> 16) & 1u);
    return (u16)((v.u + r) >> 16);
}

// async global->LDS, 16B per lane. LDS dest must be linear (base + lane*16).
__device__ __forceinline__ void gload16(const void* g, void* l) {
    auto gg = reinterpret_cast<const __attribute__((address_space(1))) unsigned*>(
        reinterpret_cast<uintptr_t>(g));
    auto ll = reinterpret_cast<__attribute__((address_space(3))) unsigned*>(
        reinterpret_cast<uintptr_t>(l));
    __builtin_amdgcn_global_load_lds(gg, ll, 16, 0, 0);
}

// ---------------------------------------------------------------------------
// Weight cast+transpose: W [1024,1024] f32 -> Wt [N][K] bf16 (4 matrices, z)
// ---------------------------------------------------------------------------
__global__ __launch_bounds__(256) void wtrans_kernel(
    const float* __restrict__ W0, const float* __restrict__ W1,
    const float* __restrict__ W2, const float* __restrict__ W3,
    u16* __restrict__ T0, u16* __restrict__ T1, u16* __restrict__ T2, u16* __restrict__ T3)
{
    __shared__ __align__(16) u16 Ts[64][72];
    const float* W = blockIdx.z == 0 ? W0 : blockIdx.z == 1 ? W1 : blockIdx.z == 2 ? W2 : W3;
    u16*         T = blockIdx.z == 0 ? T0 : blockIdx.z == 1 ? T1 : blockIdx.z == 2 ? T2 : T3;
    const int t = threadIdx.x;
    const int r0 = blockIdx.y * 64, c0 = blockIdx.x * 64;
    const int row = t >> 2, qd = t & 3;

    const float* src = W + (size_t)(r0 + row) * 1024 + c0 + qd * 16;
    u16 tmp[16];
    #pragma unroll
    for (int j = 0; j < 16; j += 4) {
        f4 v = *(const f4*)(src + j);
        tmp[j] = f2bf(v[0]); tmp[j+1] = f2bf(v[1]); tmp[j+2] = f2bf(v[2]); tmp[j+3] = f2bf(v[3]);
    }
    #pragma unroll
    for (int j = 0; j < 16; j++) Ts[row][qd * 16 + j] = tmp[j];
    __syncthreads();
    short8 o0, o1;
    #pragma unroll
    for (int j = 0; j < 8; j++) { o0[j] = (short)Ts[qd*16 + j][row]; o1[j] = (short)Ts[qd*16 + 8 + j][row]; }
    u16* dst = T + (size_t)(c0 + row) * 1024 + r0 + qd * 16;
    *(short8*)dst = o0;
    *(short8*)(dst + 8) = o1;
}

// ---------------------------------------------------------------------------
// Per-head V transpose: vp [B,S,D] bf16 -> vt [B*H][64][S] bf16
// ---------------------------------------------------------------------------
__global__ __launch_bounds__(256) void vtrans_kernel(const u16* __restrict__ vp, u16* __restrict__ vt)
{
    __shared__ __align__(16) u16 Vs[64][72];
    const int t = threadIdx.x;
    const int s0 = blockIdx.x * 64;
    const int bh = blockIdx.y, b = bh >> 4, h = bh & 15;
    #pragma unroll
    for (int i = 0; i < 2; i++) {
        int c = t + 256 * i, row = c >> 3, ch = c & 7;
        *(short8*)(&Vs[row][ch * 8]) =
            *(const short8*)(vp + ((size_t)b * S_ + s0 + row) * D_ + h * 64 + ch * 8);
    }
    __syncthreads();
    #pragma unroll
    for (int i = 0; i < 2; i++) {
        int c = t + 256 * i, d = c >> 3, ch = c & 7;
        short8 o;
        #pragma unroll
        for (int j = 0; j < 8; j++) o[j] = (short)Vs[ch * 8 + j][d];
        *(short8*)(vt + ((size_t)bh * 64 + d) * S_ + s0 + ch * 8) = o;
    }
}

// ---------------------------------------------------------------------------
// GEMM: C[M,N] = (A[M,K] @ Bt[N,K]^T + bias) * scale.  128x128 tile, BK=32,
// 4 waves, 4x4 frags. A: reg-prefetch staged (swizzled ds_write). B: async
// global_load_lds double-buffered with pre-swizzled global source.
// z-batched (3 independent GEMMs per launch).
// ---------------------------------------------------------------------------
struct Stage { short8 h[2]; };

template<int A_IS_F32>
__device__ __forceinline__ void stage_load(Stage& st, const void* Aptr, int row0, int K, int k0, int t) {
    if constexpr (A_IS_F32) {
        const float* Af = (const float*)Aptr;
        const int row = t >> 1, half = t & 1;
        const float* p = Af + (size_t)(row0 + row) * K + k0 + half * 16;
        #pragma unroll
        for (int j = 0; j < 2; j++) {
            f4 v0 = *(const f4*)(p + j * 8);
            f4 v1 = *(const f4*)(p + j * 8 + 4);
            short8 hh;
            hh[0]=(short)f2bf(v0[0]); hh[1]=(short)f2bf(v0[1]); hh[2]=(short)f2bf(v0[2]); hh[3]=(short)f2bf(v0[3]);
            hh[4]=(short)f2bf(v1[0]); hh[5]=(short)f2bf(v1[1]); hh[6]=(short)f2bf(v1[2]); hh[7]=(short)f2bf(v1[3]);
            st.h[j] = hh;
        }
    } else {
        const u16* Ah = (const u16*)Aptr;
        #pragma unroll
        for (int j = 0; j < 2; j++) {
            int c = 2 * t + j, row = c >> 2, ch = c & 3;
            st.h[j] = *(const short8*)(Ah + (size_t)(row0 + row) * K + k0 + ch * 8);
        }
    }
}

template<int A_IS_F32>
__device__ __forceinline__ void stage_store(const Stage& st, u16* Ls, int t) {
    if constexpr (A_IS_F32) {
        const int row = t >> 1, half = t & 1;
        #pragma unroll
        for (int j = 0; j < 2; j++) {
            int byteo = half * 32 + j * 16;
            *(short8*)((char*)Ls + row * 64 + (byteo ^ ((row & 3) << 4))) = st.h[j];
        }
    } else {
        #pragma unroll
        for (int j = 0; j < 2; j++) {
            int c = 2 * t + j, row = c >> 2, ch = c & 3;
            *(short8*)((char*)Ls + row * 64 + ((ch * 16) ^ ((row & 3) << 4))) = st.h[j];
        }
    }
}

template<int A_IS_F32, int OUT_IS_F32>
__global__ __launch_bounds__(256, 3)
void gemm_bt(const void* __restrict__ A0, const void* __restrict__ A1, const void* __restrict__ A2,
             const u16* __restrict__ Bt0, const u16* __restrict__ Bt1, const u16* __restrict__ Bt2,
             const float* __restrict__ bi0, const float* __restrict__ bi1, const float* __restrict__ bi2,
             void* __restrict__ C0, void* __restrict__ C1, void* __restrict__ C2,
             int M, int N, int K, float sc0, float sc1, float sc2)
{
    __shared__ __align__(16) u16 As[128 * 32];
    __shared__ __align__(16) u16 Bs[2][128 * 32];

    const int z = blockIdx.z;
    const void*  Aptr  = z == 0 ? A0  : z == 1 ? A1  : A2;
    const u16*   Bt    = z == 0 ? Bt0 : z == 1 ? Bt1 : Bt2;
    const float* bias  = z == 0 ? bi0 : z == 1 ? bi1 : bi2;
    void*        Cptr  = z == 0 ? C0  : z == 1 ? C1  : C2;
    const float  scale = z == 0 ? sc0 : z == 1 ? sc1 : sc2;

    const int t = threadIdx.x;
    const int w = t >> 6, l = t & 63, lr = l >> 4, lc = l & 15;
    const int wr = w >> 1, wc = w & 1;
    const int row0 = blockIdx.y * 128, col0 = blockIdx.x * 128;
    const int NI = K >> 5;

    // B tile issue: rows of Bt (64B each, 4 chunks), chunk pre-swizzled ^(row&3)
    auto issueB = [&](int i, int buf) {
        #pragma unroll
        for (int j = 0; j < 2; j++) {
            int off = j * 256 + t;                  // 16B unit
            int row = off >> 2, ch = off & 3;
            const char* src = (const char*)Bt + (((size_t)(col0 + row) * K + i * 32) << 1)
                              + ((ch ^ (row & 3)) << 4);
            gload16(src, (char*)Bs[buf] + off * 16);
        }
    };

    f32x4 acc[4][4] = {};
    Stage sa;
    stage_load<A_IS_F32>(sa, Aptr, row0, K, 0, t);
    issueB(0, 0);

    for (int i = 0; i < NI; i++) {
        __syncthreads();                            // (a): prev reads done; drains B(i)/A(i) loads
        stage_store<A_IS_F32>(sa, As, t);
        __syncthreads();                            // (b): As + Bs[i&1] ready
        const int kn = (i + 1 < NI) ? (i + 1) * 32 : 0;
        stage_load<A_IS_F32>(sa, Aptr, row0, K, kn, t);   // flies during MFMA
        if (i + 1 < NI) issueB(i + 1, (i + 1) & 1);       // flies during MFMA

        short8 af[4], bf_[4];
        #pragma unroll
        for (int mm = 0; mm < 4; mm++) {
            int r = wr * 64 + mm * 16 + lc;
            af[mm] = *(const short8*)((const char*)As + r * 64 + ((lr * 16) ^ ((r & 3) << 4)));
        }
        #pragma unroll
        for (int nn = 0; nn < 4; nn++) {
            int r = wc * 64 + nn * 16 + lc;
            bf_[nn] = *(const short8*)((const char*)Bs[i & 1] + r * 64 + ((lr * 16) ^ ((r & 3) << 4)));
        }
        #pragma unroll
        for (int mm = 0; mm < 4; mm++)
            #pragma unroll
            for (int nn = 0; nn < 4; nn++)
                acc[mm][nn] = __builtin_amdgcn_mfma_f32_16x16x32_bf16(af[mm], bf_[nn], acc[mm][nn], 0, 0, 0);
    }

    float bv[4];
    #pragma unroll
    for (int nn = 0; nn < 4; nn++) bv[nn] = bias[col0 + wc * 64 + nn * 16 + lc];

    #pragma unroll
    for (int mm = 0; mm < 4; mm++) {
        const int row = row0 + wr * 64 + mm * 16 + lr * 4;
        #pragma unroll
        for (int nn = 0; nn < 4; nn++) {
            const int col = col0 + wc * 64 + nn * 16 + lc;
            #pragma unroll
            for (int r = 0; r < 4; r++) {
                float vv = (acc[mm][nn][r] + bv[nn]) * scale;
                if constexpr (OUT_IS_F32) ((float*)Cptr)[(size_t)(row + r) * N + col] = vv;
                else                      ((u16*) Cptr)[(size_t)(row + r) * N + col] = f2bf(vv);
            }
        }
    }
}

// ---------------------------------------------------------------------------
// Fused attention. Block = 64 q-rows x (one b,h). 4 waves x 16 rows each.
// KVBLK=64, double-buffered K/V via global_load_lds (pre-swizzled source),
// ONE barrier per tile (loads for tile t+1 fly under tile t's compute).
// Softmax without running max (scores are O(5); exp safe in f32; identical
// math to reference). qp pre-scaled by 1/8.
// ---------------------------------------------------------------------------
__global__ __launch_bounds__(256, 3)
void attn_kernel(const u16* __restrict__ qp, const u16* __restrict__ kp,
                 const u16* __restrict__ vt, float* __restrict__ Pout,
                 u16* __restrict__ xout)
{
    __shared__ __align__(16) u16 Qs[64 * 64];       //  8KB, 128B rows, swizzled
    __shared__ __align__(16) u16 Ks[2][64 * 64];    // 16KB, [s=64][d=64], swizzled via source
    __shared__ __align__(16) u16 Vts[2][64 * 64];   // 16KB, [d=64][s=64], swizzled via source
    __shared__ __align__(16) u16 Ps[4][16][72];     //  9KB, per-wave P, 144B rows

    const int t = threadIdx.x;
    const int w = t >> 6, l = t & 63, lr = l >> 4, lc = l & 15;
    const int q0 = blockIdx.x * 64;
    const int bh = blockIdx.y, b = bh >> 4, h = bh & 15;
    const float L2E = 1.4426950408889634f;
    constexpr int NT = S_ / 64;                     // 32 tiles

    auto issueK = [&](int kt, int buf) {
        #pragma unroll
        for (int i = 0; i < 2; i++) {
            int off = i * 256 + t, row = off >> 3, ch = off & 7;
            const char* src = (const char*)kp + ((((size_t)b * S_ + kt * 64 + row) * D_ + h * 64) << 1)
                              + ((ch ^ (row & 7)) << 4);
            gload16(src, (char*)Ks[buf] + off * 16);
        }
    };
    auto issueV = [&](int kt, int buf) {
        #pragma unroll
        for (int i = 0; i < 2; i++) {
            int off = i * 256 + t, row = off >> 3, ch = off & 7;
            const char* src = (const char*)vt + ((((size_t)bh * 64 + row) * S_ + kt * 64) << 1)
                              + ((ch ^ (row & 7)) << 4);
            gload16(src, (char*)Vts[buf] + off * 16);
        }
    };

    // stage Q tile [64 rows][64 d] (reg-staged, swizzled), overlap with K0 issue
    #pragma unroll
    for (int i = 0; i < 2; i++) {
        int c = t + 256 * i, row = c >> 3, ch = c & 7;
        short8 vq = *(const short8*)(qp + ((size_t)b * S_ + q0 + row) * D_ + h * 64 + ch * 8);
        *(short8*)((char*)Qs + row * 128 + ((ch * 16) ^ ((row & 7) << 4))) = vq;
    }
    issueK(0, 0);
    __syncthreads();

    short8 qf[2];
    {
        int r = w * 16 + lc, sw = (r & 7) << 4;
        const char* qb = (const char*)Qs + r * 128;
        qf[0] = *(const short8*)(qb + ((lr * 16) ^ sw));
        qf[1] = *(const short8*)(qb + ((64 + lr * 16) ^ sw));
    }

    // ---------------- pass 1: per-row sum of exp(s) ----------------
    float sum_[4] = {0.f, 0.f, 0.f, 0.f};
    for (int kt = 0; kt < NT; kt++) {
        const int p = kt & 1;
        if (kt + 1 < NT) issueK(kt + 1, p ^ 1);
        const char* Kb = (const char*)Ks[p];
        f32x4 sacc[4] = {};
        #pragma unroll
        for (int f = 0; f < 4; f++) {
            int r = f * 16 + lc, sw = (r & 7) << 4;
            const char* kb = Kb + r * 128;
            short8 b0 = *(const short8*)(kb + ((lr * 16) ^ sw));
            short8 b1 = *(const short8*)(kb + ((64 + lr * 16) ^ sw));
            sacc[f] = __builtin_amdgcn_mfma_f32_16x16x32_bf16(qf[0], b0, sacc[f], 0, 0, 0);
            sacc[f] = __builtin_amdgcn_mfma_f32_16x16x32_bf16(qf[1], b1, sacc[f], 0, 0, 0);
        }
        #pragma unroll
        for (int f = 0; f < 4; f++)
            #pragma unroll
            for (int r = 0; r < 4; r++)
                sum_[r] += exp2f(sacc[f][r] * L2E);
        __syncthreads();                            // drains issued loads; orders buffer reuse
    }
    #pragma unroll
    for (int o = 1; o < 16; o <<= 1)
        #pragma unroll
        for (int r = 0; r < 4; r++) sum_[r] += __shfl_xor(sum_[r], o);
    float inv_[4];
    #pragma unroll
    for (int r = 0; r < 4; r++) inv_[r] = 1.0f / sum_[r];

    // ---------------- pass 2: write P (f32), PV accumulate ----------------
    f32x4 xacc[4] = {};
    u16* psw = &Ps[w][0][0];
    float* pout_base = Pout + ((size_t)bh * S_ + q0 + w * 16 + lr * 4) * S_ + lc;

    issueK(0, 0); issueV(0, 0);
    __syncthreads();
    for (int kt = 0; kt < NT; kt++) {
        const int p = kt & 1;
        if (kt + 1 < NT) { issueK(kt + 1, p ^ 1); issueV(kt + 1, p ^ 1); }
        const char* Kb = (const char*)Ks[p];
        const char* Vb = (const char*)Vts[p];

        f32x4 sacc[4] = {};
        #pragma unroll
        for (int f = 0; f < 4; f++) {
            int r = f * 16 + lc, sw = (r & 7) << 4;
            const char* kb = Kb + r * 128;
            short8 b0 = *(const short8*)(kb + ((lr * 16) ^ sw));
            short8 b1 = *(const short8*)(kb + ((64 + lr * 16) ^ sw));
            sacc[f] = __builtin_amdgcn_mfma_f32_16x16x32_bf16(qf[0], b0, sacc[f], 0, 0, 0);
            sacc[f] = __builtin_amdgcn_mfma_f32_16x16x32_bf16(qf[1], b1, sacc[f], 0, 0, 0);
        }

        #pragma unroll
        for (int f = 0; f < 4; f++) {
            #pragma unroll
            for (int r = 0; r < 4; r++) {
                float pp = exp2f(sacc[f][r] * L2E) * inv_[r];
                pout_base[(size_t)r * S_ + kt * 64 + f * 16] = pp;
                psw[(lr * 4 + r) * 72 + f * 16 + lc] = f2bf(pp);
            }
        }

        #pragma unroll
        for (int kk = 0; kk < 2; kk++) {
            short8 pa = *(const short8*)((const char*)psw + lc * 144 + kk * 64 + lr * 16);
            #pragma unroll
            for (int n = 0; n < 4; n++) {
                int rr = n * 16 + lc;
                short8 vb = *(const short8*)(Vb + rr * 128 + ((kk * 64 + lr * 16) ^ ((rr & 7) << 4)));
                xacc[n] = __builtin_amdgcn_mfma_f32_16x16x32_bf16(pa, vb, xacc[n], 0, 0, 0);
            }
        }
        __syncthreads();                            // drains issued loads; orders buffer reuse
    }

    #pragma unroll
    for (int n = 0; n < 4; n++) {
        #pragma unroll
        for (int r = 0; r < 4; r++) {
            int row = q0 + w * 16 + lr * 4 + r;
            int col = h * 64 + n * 16 + lc;
            xout[((size_t)b * S_ + row) * D_ + col] = f2bf(xacc[n][r]);
        }
    }
}

// ---------------------------------------------------------------------------
extern "C" void kernel_launch(void* const* d_in, const int* in_sizes, int n_in,
                              void* d_out, int out_size, void* d_ws, size_t ws_size,
                              hipStream_t stream)
{
    const float* qin = (const float*)d_in[0];
    const float* kin = (const float*)d_in[1];
    const float* vin = (const float*)d_in[2];
    const float* Wq  = (const float*)d_in[3];
    const float* bq  = (const float*)d_in[4];
    const float* Wk  = (const float*)d_in[5];
    const float* bk  = (const float*)d_in[6];
    const float* Wv  = (const float*)d_in[7];
    const float* bv  = (const float*)d_in[8];
    const float* Wo  = (const float*)d_in[9];
    const float* bo  = (const float*)d_in[10];

    // ws layout (u16 elements): 4x Wt (1M each) | qp | kp | vp (4M each) | vt | x
    u16* base = (u16*)d_ws;
    u16* Wqt = base;
    u16* Wkt = base + 1048576;
    u16* Wvt = base + 2097152;
    u16* Wot = base + 3145728;
    u16* qpb = base + 4194304;
    u16* kpb = base + 8388608;
    u16* vpb = base + 12582912;
    u16* vtb = base + 16777216;
    u16* xb  = base + 20971520;   // total ~50MB

    float* out  = (float*)d_out;
    float* Pout = out + OUT_ELEMS;

    const int M = B_ * S_;  // 4096

    wtrans_kernel<<<dim3(16, 16, 4), 256, 0, stream>>>(Wq, Wk, Wv, Wo, Wqt, Wkt, Wvt, Wot);
    // batched q/k/v projection; qp scaled by 1/sqrt(DK) = 0.125
    gemm_bt<1, 0><<<dim3(8, 32, 3), 256, 0, stream>>>(
        qin, kin, vin, Wqt, Wkt, Wvt, bq, bk, bv, qpb, kpb, vpb, M, D_, D_, 0.125f, 1.0f, 1.0f);
    vtrans_kernel<<<dim3(32, 32), 256, 0, stream>>>(vpb, vtb);
    attn_kernel<<<dim3(32, 32), 256, 0, stream>>>(qpb, kpb, vtb, Pout, xb);
    gemm_bt<0, 1><<<dim3(8, 32, 1), 256, 0, stream>>>(
        xb, xb, xb, Wot, Wot, Wot, bo, bo, bo, out, out, out, M, D_, D_, 1.0f, 1.0f, 1.0f);
}

// Round 4
// 295.876 us; speedup vs baseline: 1.3653x; 1.1088x over previous
//
#include <hip/hip_runtime.h>
#include <hip/hip_bf16.h>
#include <stdint.h>
#include <stddef.h>

typedef unsigned short u16;
typedef __attribute__((ext_vector_type(8))) short short8;   // 8 x bf16 MFMA A/B frag
typedef __attribute__((ext_vector_type(4))) short bfx4;     // 4 x bf16 (8B)
typedef __attribute__((ext_vector_type(4))) float f32x4;    // MFMA C/D frag
typedef __attribute__((ext_vector_type(4))) float f4;

constexpr int B_ = 2, S_ = 2048, D_ = 1024, H_ = 16;
constexpr size_t OUT_ELEMS = (size_t)B_ * S_ * D_;          // 4,194,304

__device__ __forceinline__ u16 f2bf(float f) {              // RNE f32 -> bf16
    union { float f; unsigned u; } v; v.f = f;
    unsigned r = 0x7FFFu + ((v.u >> 16) & 1u);
    return (u16)((v.u + r) >> 16);
}

// async global->LDS, 16B per lane. LDS dest must be linear (base + lane*16).
__device__ __forceinline__ void gload16(const void* g, void* l) {
    auto gg = reinterpret_cast<const __attribute__((address_space(1))) unsigned*>(
        reinterpret_cast<uintptr_t>(g));
    auto ll = reinterpret_cast<__attribute__((address_space(3))) unsigned*>(
        reinterpret_cast<uintptr_t>(l));
    __builtin_amdgcn_global_load_lds(gg, ll, 16, 0, 0);
}

// ---------------------------------------------------------------------------
// Weight cast+transpose: W [1024,1024] f32 -> Wt [N][K] bf16 (4 matrices, z)
// ---------------------------------------------------------------------------
__global__ __launch_bounds__(256) void wtrans_kernel(
    const float* __restrict__ W0, const float* __restrict__ W1,
    const float* __restrict__ W2, const float* __restrict__ W3,
    u16* __restrict__ T0, u16* __restrict__ T1, u16* __restrict__ T2, u16* __restrict__ T3)
{
    __shared__ __align__(16) u16 Ts[64][72];
    const float* W = blockIdx.z == 0 ? W0 : blockIdx.z == 1 ? W1 : blockIdx.z == 2 ? W2 : W3;
    u16*         T = blockIdx.z == 0 ? T0 : blockIdx.z == 1 ? T1 : blockIdx.z == 2 ? T2 : T3;
    const int t = threadIdx.x;
    const int r0 = blockIdx.y * 64, c0 = blockIdx.x * 64;
    const int row = t >> 2, qd = t & 3;

    const float* src = W + (size_t)(r0 + row) * 1024 + c0 + qd * 16;
    u16 tmp[16];
    #pragma unroll
    for (int j = 0; j < 16; j += 4) {
        f4 v = *(const f4*)(src + j);
        tmp[j] = f2bf(v[0]); tmp[j+1] = f2bf(v[1]); tmp[j+2] = f2bf(v[2]); tmp[j+3] = f2bf(v[3]);
    }
    #pragma unroll
    for (int j = 0; j < 16; j++) Ts[row][qd * 16 + j] = tmp[j];
    __syncthreads();
    short8 o0, o1;
    #pragma unroll
    for (int j = 0; j < 8; j++) { o0[j] = (short)Ts[qd*16 + j][row]; o1[j] = (short)Ts[qd*16 + 8 + j][row]; }
    u16* dst = T + (size_t)(c0 + row) * 1024 + r0 + qd * 16;
    *(short8*)dst = o0;
    *(short8*)(dst + 8) = o1;
}

// ---------------------------------------------------------------------------
// Per-head V transpose: vp [B,S,D] bf16 -> vt [B*H][64][S] bf16
// ---------------------------------------------------------------------------
__global__ __launch_bounds__(256) void vtrans_kernel(const u16* __restrict__ vp, u16* __restrict__ vt)
{
    __shared__ __align__(16) u16 Vs[64][72];
    const int t = threadIdx.x;
    const int s0 = blockIdx.x * 64;
    const int bh = blockIdx.y, b = bh >> 4, h = bh & 15;
    #pragma unroll
    for (int i = 0; i < 2; i++) {
        int c = t + 256 * i, row = c >> 3, ch = c & 7;
        *(short8*)(&Vs[row][ch * 8]) =
            *(const short8*)(vp + ((size_t)b * S_ + s0 + row) * D_ + h * 64 + ch * 8);
    }
    __syncthreads();
    #pragma unroll
    for (int i = 0; i < 2; i++) {
        int c = t + 256 * i, d = c >> 3, ch = c & 7;
        short8 o;
        #pragma unroll
        for (int j = 0; j < 8; j++) o[j] = (short)Vs[ch * 8 + j][d];
        *(short8*)(vt + ((size_t)bh * 64 + d) * S_ + s0 + ch * 8) = o;
    }
}

// ---------------------------------------------------------------------------
// GEMM: C[M,N] = (A[M,K] @ Bt[N,K]^T + bias) * scale.  128x128 tile, BK=32,
// 4 waves, 4x4 frags. ONE barrier per K-step. B (and bf16-A) via
// global_load_lds with pre-swizzled source; f32-A reg-staged double-buffered.
// ---------------------------------------------------------------------------
struct Stage { short8 h[2]; };

__device__ __forceinline__ void stage_load_f32(Stage& st, const float* Af, int row0, int K, int k0, int t) {
    const int row = t >> 1, half = t & 1;
    const float* p = Af + (size_t)(row0 + row) * K + k0 + half * 16;
    #pragma unroll
    for (int j = 0; j < 2; j++) {
        f4 v0 = *(const f4*)(p + j * 8);
        f4 v1 = *(const f4*)(p + j * 8 + 4);
        short8 hh;
        hh[0]=(short)f2bf(v0[0]); hh[1]=(short)f2bf(v0[1]); hh[2]=(short)f2bf(v0[2]); hh[3]=(short)f2bf(v0[3]);
        hh[4]=(short)f2bf(v1[0]); hh[5]=(short)f2bf(v1[1]); hh[6]=(short)f2bf(v1[2]); hh[7]=(short)f2bf(v1[3]);
        st.h[j] = hh;
    }
}

__device__ __forceinline__ void stage_store_f32(const Stage& st, u16* Ls, int t) {
    const int row = t >> 1, half = t & 1;
    #pragma unroll
    for (int j = 0; j < 2; j++) {
        int byteo = half * 32 + j * 16;
        *(short8*)((char*)Ls + row * 64 + (byteo ^ ((row & 3) << 4))) = st.h[j];
    }
}

template<int A_IS_F32, int OUT_IS_F32>
__global__ __launch_bounds__(256, 3)
void gemm_bt(const void* __restrict__ A0, const void* __restrict__ A1, const void* __restrict__ A2,
             const u16* __restrict__ Bt0, const u16* __restrict__ Bt1, const u16* __restrict__ Bt2,
             const float* __restrict__ bi0, const float* __restrict__ bi1, const float* __restrict__ bi2,
             void* __restrict__ C0, void* __restrict__ C1, void* __restrict__ C2,
             int M, int N, int K, float sc0, float sc1, float sc2)
{
    __shared__ __align__(16) u16 As[2][128 * 32];
    __shared__ __align__(16) u16 Bs[2][128 * 32];

    const int z = blockIdx.z;
    const void*  Aptr  = z == 0 ? A0  : z == 1 ? A1  : A2;
    const u16*   Bt    = z == 0 ? Bt0 : z == 1 ? Bt1 : Bt2;
    const float* bias  = z == 0 ? bi0 : z == 1 ? bi1 : bi2;
    void*        Cptr  = z == 0 ? C0  : z == 1 ? C1  : C2;
    const float  scale = z == 0 ? sc0 : z == 1 ? sc1 : sc2;

    const int t = threadIdx.x;
    const int w = t >> 6, l = t & 63, lr = l >> 4, lc = l & 15;
    const int wr = w >> 1, wc = w & 1;
    const int row0 = blockIdx.y * 128, col0 = blockIdx.x * 128;
    const int NI = K >> 5;

    // DMA a [128 rows][32 k] bf16 tile (rows of 64B = 4 chunks, pre-swizzled ^(row&3))
    auto issueT = [&](const u16* P, int r0_, int i, u16* dst) {
        #pragma unroll
        for (int j = 0; j < 2; j++) {
            int off = j * 256 + t;                  // 16B unit
            int row = off >> 2, ch = off & 3;
            const char* src = (const char*)P + (((size_t)(r0_ + row) * K + i * 32) << 1)
                              + ((ch ^ (row & 3)) << 4);
            gload16(src, (char*)dst + off * 16);
        }
    };

    f32x4 acc[4][4] = {};
    Stage sa;
    issueT(Bt, col0, 0, Bs[0]);
    if constexpr (A_IS_F32) {
        stage_load_f32(sa, (const float*)Aptr, row0, K, 0, t);
        stage_store_f32(sa, As[0], t);
        stage_load_f32(sa, (const float*)Aptr, row0, K, 32, t);
    } else {
        issueT((const u16*)Aptr, row0, 0, As[0]);
    }
    __syncthreads();

    for (int i = 0; i < NI; i++) {
        const int p = i & 1;
        if (i + 1 < NI) {
            issueT(Bt, col0, i + 1, Bs[p ^ 1]);
            if constexpr (A_IS_F32) {
                stage_store_f32(sa, As[p ^ 1], t);
                const int kn = (i + 2 < NI) ? (i + 2) * 32 : 0;
                stage_load_f32(sa, (const float*)Aptr, row0, K, kn, t);
            } else {
                issueT((const u16*)Aptr, row0, i + 1, As[p ^ 1]);
            }
        }

        short8 af[4], bf_[4];
        #pragma unroll
        for (int mm = 0; mm < 4; mm++) {
            int r = wr * 64 + mm * 16 + lc;
            af[mm] = *(const short8*)((const char*)As[p] + r * 64 + ((lr * 16) ^ ((r & 3) << 4)));
        }
        #pragma unroll
        for (int nn = 0; nn < 4; nn++) {
            int r = wc * 64 + nn * 16 + lc;
            bf_[nn] = *(const short8*)((const char*)Bs[p] + r * 64 + ((lr * 16) ^ ((r & 3) << 4)));
        }
        #pragma unroll
        for (int mm = 0; mm < 4; mm++)
            #pragma unroll
            for (int nn = 0; nn < 4; nn++)
                acc[mm][nn] = __builtin_amdgcn_mfma_f32_16x16x32_bf16(af[mm], bf_[nn], acc[mm][nn], 0, 0, 0);
        __syncthreads();
    }

    float bv[4];
    #pragma unroll
    for (int nn = 0; nn < 4; nn++) bv[nn] = bias[col0 + wc * 64 + nn * 16 + lc];

    #pragma unroll
    for (int mm = 0; mm < 4; mm++) {
        const int row = row0 + wr * 64 + mm * 16 + lr * 4;
        #pragma unroll
        for (int nn = 0; nn < 4; nn++) {
            const int col = col0 + wc * 64 + nn * 16 + lc;
            #pragma unroll
            for (int r = 0; r < 4; r++) {
                float vv = (acc[mm][nn][r] + bv[nn]) * scale;
                if constexpr (OUT_IS_F32) ((float*)Cptr)[(size_t)(row + r) * N + col] = vv;
                else                      ((u16*) Cptr)[(size_t)(row + r) * N + col] = f2bf(vv);
            }
        }
    }
}

// ---------------------------------------------------------------------------
// Fused attention, SWAPPED QK^T: sacc = mfma(K_frag, Q_frag) so each lane
// owns P[q=lc][k=lr*4+r (+16f)] -> P stays in registers (PV A-frag built
// in-lane; V B-frag read as 2x ds_read_b64 with matching permuted k-order),
// Pout written as dwordx4. Block = 64 q-rows x (b,h); 4 waves x 16 q-rows.
// KVBLK=64, double-buffered via global_load_lds, ONE barrier per tile.
// No-max softmax (scores ~N(0,1); exact same math as reference).
// ---------------------------------------------------------------------------
__global__ __launch_bounds__(256, 4)
void attn_kernel(const u16* __restrict__ qp, const u16* __restrict__ kp,
                 const u16* __restrict__ vt, float* __restrict__ Pout,
                 u16* __restrict__ xout)
{
    __shared__ __align__(16) u16 Qs[64 * 64];       //  8KB [q][d], swizzled rows 128B
    __shared__ __align__(16) u16 Ks[2][64 * 64];    // 16KB [k][d], source-swizzled
    __shared__ __align__(16) u16 Vts[2][64 * 64];   // 16KB [d][k], source-swizzled

    const int t = threadIdx.x;
    const int w = t >> 6, l = t & 63, lr = l >> 4, lc = l & 15;
    // XCD-bijective swizzle: 1024 blocks -> 8 chunks of 128 (= 4 bh each)
    const int bid = blockIdx.x;
    const int s = ((bid & 7) << 7) | (bid >> 3);
    const int q0 = (s & 31) * 64;
    const int bh = s >> 5, b = bh >> 4, h = bh & 15;
    const float L2E = 1.4426950408889634f;
    constexpr int NT = S_ / 64;                     // 32 tiles

    auto issueK = [&](int kt, int buf) {
        #pragma unroll
        for (int i = 0; i < 2; i++) {
            int off = i * 256 + t, row = off >> 3, ch = off & 7;
            const char* src = (const char*)kp + ((((size_t)b * S_ + kt * 64 + row) * D_ + h * 64) << 1)
                              + ((ch ^ (row & 7)) << 4);
            gload16(src, (char*)Ks[buf] + off * 16);
        }
    };
    auto issueV = [&](int kt, int buf) {
        #pragma unroll
        for (int i = 0; i < 2; i++) {
            int off = i * 256 + t, row = off >> 3, ch = off & 7;
            const char* src = (const char*)vt + ((((size_t)bh * 64 + row) * S_ + kt * 64) << 1)
                              + ((ch ^ (row & 7)) << 4);
            gload16(src, (char*)Vts[buf] + off * 16);
        }
    };

    issueK(0, 0);
    // stage Q tile [64 q][64 d] (reg-staged, swizzled)
    #pragma unroll
    for (int i = 0; i < 2; i++) {
        int c = t + 256 * i, row = c >> 3, ch = c & 7;
        short8 vq = *(const short8*)(qp + ((size_t)b * S_ + q0 + row) * D_ + h * 64 + ch * 8);
        *(short8*)((char*)Qs + row * 128 + ((ch * 16) ^ ((row & 7) << 4))) = vq;
    }
    __syncthreads();

    short8 qf[2];
    {
        int r = w * 16 + lc, sw = (r & 7) << 4;
        const char* qb = (const char*)Qs + r * 128;
        qf[0] = *(const short8*)(qb + ((lr * 16) ^ sw));
        qf[1] = *(const short8*)(qb + ((64 + lr * 16) ^ sw));
    }

    // ---------------- pass 1: per-lane sum of exp(s) over own k-slice ----------------
    float sum = 0.f;
    for (int kt = 0; kt < NT; kt++) {
        const int p = kt & 1;
        if (kt + 1 < NT) issueK(kt + 1, p ^ 1);
        const char* Kb = (const char*)Ks[p];
        #pragma unroll
        for (int f = 0; f < 4; f++) {
            int r = f * 16 + lc, sw = (r & 7) << 4;
            const char* kb = Kb + r * 128;
            short8 k0 = *(const short8*)(kb + ((lr * 16) ^ sw));
            short8 k1 = *(const short8*)(kb + ((64 + lr * 16) ^ sw));
            f32x4 sacc = {};
            sacc = __builtin_amdgcn_mfma_f32_16x16x32_bf16(k0, qf[0], sacc, 0, 0, 0);
            sacc = __builtin_amdgcn_mfma_f32_16x16x32_bf16(k1, qf[1], sacc, 0, 0, 0);
            sum += exp2f(sacc[0] * L2E) + exp2f(sacc[1] * L2E)
                 + exp2f(sacc[2] * L2E) + exp2f(sacc[3] * L2E);
        }
        __syncthreads();
    }
    sum += __shfl_xor(sum, 16);
    sum += __shfl_xor(sum, 32);
    const float inv = 1.0f / sum;

    // ---------------- pass 2: P (regs) -> Pout dwordx4 + in-register PV ----------------
    f32x4 xacc[4] = {};
    float* pbase = Pout + ((size_t)bh * S_ + q0 + w * 16 + lc) * S_ + lr * 4;

    issueK(0, 0); issueV(0, 0);
    __syncthreads();
    for (int kt = 0; kt < NT; kt++) {
        const int p = kt & 1;
        if (kt + 1 < NT) { issueK(kt + 1, p ^ 1); issueV(kt + 1, p ^ 1); }
        const char* Kb = (const char*)Ks[p];
        const char* Vb = (const char*)Vts[p];

        #pragma unroll
        for (int kk = 0; kk < 2; kk++) {
            union { unsigned u[4]; short8 s8; } pu;
            #pragma unroll
            for (int fo = 0; fo < 2; fo++) {
                const int f = kk * 2 + fo;
                int r = f * 16 + lc, sw = (r & 7) << 4;
                const char* kb = Kb + r * 128;
                short8 k0 = *(const short8*)(kb + ((lr * 16) ^ sw));
                short8 k1 = *(const short8*)(kb + ((64 + lr * 16) ^ sw));
                f32x4 sacc = {};
                sacc = __builtin_amdgcn_mfma_f32_16x16x32_bf16(k0, qf[0], sacc, 0, 0, 0);
                sacc = __builtin_amdgcn_mfma_f32_16x16x32_bf16(k1, qf[1], sacc, 0, 0, 0);
                f32x4 pv_;
                pv_[0] = exp2f(sacc[0] * L2E) * inv;
                pv_[1] = exp2f(sacc[1] * L2E) * inv;
                pv_[2] = exp2f(sacc[2] * L2E) * inv;
                pv_[3] = exp2f(sacc[3] * L2E) * inv;
                *(f32x4*)(pbase + (size_t)kt * 64 + f * 16) = pv_;
                pu.u[fo * 2 + 0] = (unsigned)f2bf(pv_[0]) | ((unsigned)f2bf(pv_[1]) << 16);
                pu.u[fo * 2 + 1] = (unsigned)f2bf(pv_[2]) | ((unsigned)f2bf(pv_[3]) << 16);
            }
            const short8 pa = pu.s8;   // A-frag: P[q=lc][k = kk*32 + perm(lr,j)]
            #pragma unroll
            for (int n = 0; n < 4; n++) {
                int rr = n * 16 + lc, sw2 = (rr & 7) << 4;
                const char* vrow = Vb + rr * 128;
                union { bfx4 h[2]; short8 s8; } vu;
                vu.h[0] = *(const bfx4*)(vrow + ((kk * 64 + lr * 8) ^ sw2));
                vu.h[1] = *(const bfx4*)(vrow + ((kk * 64 + 32 + lr * 8) ^ sw2));
                xacc[n] = __builtin_amdgcn_mfma_f32_16x16x32_bf16(pa, vu.s8, xacc[n], 0, 0, 0);
            }
        }
        __syncthreads();
    }

    #pragma unroll
    for (int n = 0; n < 4; n++) {
        #pragma unroll
        for (int r = 0; r < 4; r++) {
            int row = q0 + w * 16 + lr * 4 + r;
            int col = h * 64 + n * 16 + lc;
            xout[((size_t)b * S_ + row) * D_ + col] = f2bf(xacc[n][r]);
        }
    }
}

// ---------------------------------------------------------------------------
extern "C" void kernel_launch(void* const* d_in, const int* in_sizes, int n_in,
                              void* d_out, int out_size, void* d_ws, size_t ws_size,
                              hipStream_t stream)
{
    const float* qin = (const float*)d_in[0];
    const float* kin = (const float*)d_in[1];
    const float* vin = (const float*)d_in[2];
    const float* Wq  = (const float*)d_in[3];
    const float* bq  = (const float*)d_in[4];
    const float* Wk  = (const float*)d_in[5];
    const float* bk  = (const float*)d_in[6];
    const float* Wv  = (const float*)d_in[7];
    const float* bv  = (const float*)d_in[8];
    const float* Wo  = (const float*)d_in[9];
    const float* bo  = (const float*)d_in[10];

    // ws layout (u16 elements): 4x Wt (1M each) | qp | kp | vp (4M each) | vt | x
    u16* base = (u16*)d_ws;
    u16* Wqt = base;
    u16* Wkt = base + 1048576;
    u16* Wvt = base + 2097152;
    u16* Wot = base + 3145728;
    u16* qpb = base + 4194304;
    u16* kpb = base + 8388608;
    u16* vpb = base + 12582912;
    u16* vtb = base + 16777216;
    u16* xb  = base + 20971520;   // total ~50MB

    float* out  = (float*)d_out;
    float* Pout = out + OUT_ELEMS;

    const int M = B_ * S_;  // 4096

    wtrans_kernel<<<dim3(16, 16, 4), 256, 0, stream>>>(Wq, Wk, Wv, Wo, Wqt, Wkt, Wvt, Wot);
    // batched q/k/v projection; qp scaled by 1/sqrt(DK) = 0.125
    gemm_bt<1, 0><<<dim3(8, 32, 3), 256, 0, stream>>>(
        qin, kin, vin, Wqt, Wkt, Wvt, bq, bk, bv, qpb, kpb, vpb, M, D_, D_, 0.125f, 1.0f, 1.0f);
    vtrans_kernel<<<dim3(32, 32), 256, 0, stream>>>(vpb, vtb);
    attn_kernel<<<1024, 256, 0, stream>>>(qpb, kpb, vtb, Pout, xb);
    gemm_bt<0, 1><<<dim3(8, 32, 1), 256, 0, stream>>>(
        xb, xb, xb, Wot, Wot, Wot, bo, bo, bo, out, out, out, M, D_, D_, 1.0f, 1.0f, 1.0f);
}

// Round 5
// 292.149 us; speedup vs baseline: 1.3827x; 1.0128x over previous
//
#include <hip/hip_runtime.h>
#include <hip/hip_bf16.h>
#include <stdint.h>
#include <stddef.h>

typedef unsigned short u16;
typedef __attribute__((ext_vector_type(8))) short short8;   // 8 x bf16 MFMA A/B frag
typedef __attribute__((ext_vector_type(4))) short bfx4;     // 4 x bf16 (8B)
typedef __attribute__((ext_vector_type(4))) float f32x4;    // MFMA C/D frag
typedef __attribute__((ext_vector_type(4))) float f4;

constexpr int B_ = 2, S_ = 2048, D_ = 1024, H_ = 16;
constexpr size_t OUT_ELEMS = (size_t)B_ * S_ * D_;          // 4,194,304

__device__ __forceinline__ u16 f2bf(float f) {              // RNE f32 -> bf16
    union { float f; unsigned u; } v; v.f = f;
    unsigned r = 0x7FFFu + ((v.u >> 16) & 1u);
    return (u16)((v.u + r) >> 16);
}

// async global->LDS, 16B per lane. LDS dest must be linear (base + lane*16).
__device__ __forceinline__ void gload16(const void* g, void* l) {
    auto gg = reinterpret_cast<const __attribute__((address_space(1))) unsigned*>(
        reinterpret_cast<uintptr_t>(g));
    auto ll = reinterpret_cast<__attribute__((address_space(3))) unsigned*>(
        reinterpret_cast<uintptr_t>(l));
    __builtin_amdgcn_global_load_lds(gg, ll, 16, 0, 0);
}

// ---------------------------------------------------------------------------
// Weight cast+transpose: W [1024,1024] f32 -> Wt [N][K] bf16 (4 matrices, z)
// ---------------------------------------------------------------------------
__global__ __launch_bounds__(256) void wtrans_kernel(
    const float* __restrict__ W0, const float* __restrict__ W1,
    const float* __restrict__ W2, const float* __restrict__ W3,
    u16* __restrict__ T0, u16* __restrict__ T1, u16* __restrict__ T2, u16* __restrict__ T3)
{
    __shared__ __align__(16) u16 Ts[64][72];
    const float* W = blockIdx.z == 0 ? W0 : blockIdx.z == 1 ? W1 : blockIdx.z == 2 ? W2 : W3;
    u16*         T = blockIdx.z == 0 ? T0 : blockIdx.z == 1 ? T1 : blockIdx.z == 2 ? T2 : T3;
    const int t = threadIdx.x;
    const int r0 = blockIdx.y * 64, c0 = blockIdx.x * 64;
    const int row = t >> 2, qd = t & 3;

    const float* src = W + (size_t)(r0 + row) * 1024 + c0 + qd * 16;
    u16 tmp[16];
    #pragma unroll
    for (int j = 0; j < 16; j += 4) {
        f4 v = *(const f4*)(src + j);
        tmp[j] = f2bf(v[0]); tmp[j+1] = f2bf(v[1]); tmp[j+2] = f2bf(v[2]); tmp[j+3] = f2bf(v[3]);
    }
    #pragma unroll
    for (int j = 0; j < 16; j++) Ts[row][qd * 16 + j] = tmp[j];
    __syncthreads();
    short8 o0, o1;
    #pragma unroll
    for (int j = 0; j < 8; j++) { o0[j] = (short)Ts[qd*16 + j][row]; o1[j] = (short)Ts[qd*16 + 8 + j][row]; }
    u16* dst = T + (size_t)(c0 + row) * 1024 + r0 + qd * 16;
    *(short8*)dst = o0;
    *(short8*)(dst + 8) = o1;
}

// ---------------------------------------------------------------------------
// Per-head V transpose: vp [B,S,D] bf16 -> vt [B*H][64][S] bf16
// ---------------------------------------------------------------------------
__global__ __launch_bounds__(256) void vtrans_kernel(const u16* __restrict__ vp, u16* __restrict__ vt)
{
    __shared__ __align__(16) u16 Vs[64][72];
    const int t = threadIdx.x;
    const int s0 = blockIdx.x * 64;
    const int bh = blockIdx.y, b = bh >> 4, h = bh & 15;
    #pragma unroll
    for (int i = 0; i < 2; i++) {
        int c = t + 256 * i, row = c >> 3, ch = c & 7;
        *(short8*)(&Vs[row][ch * 8]) =
            *(const short8*)(vp + ((size_t)b * S_ + s0 + row) * D_ + h * 64 + ch * 8);
    }
    __syncthreads();
    #pragma unroll
    for (int i = 0; i < 2; i++) {
        int c = t + 256 * i, d = c >> 3, ch = c & 7;
        short8 o;
        #pragma unroll
        for (int j = 0; j < 8; j++) o[j] = (short)Vs[ch * 8 + j][d];
        *(short8*)(vt + ((size_t)bh * 64 + d) * S_ + s0 + ch * 8) = o;
    }
}

// ---------------------------------------------------------------------------
// GEMM: C[M,N] = (A[M,K] @ Bt[N,K]^T + bias) * scale.  128x128 tile, BK=32,
// 4 waves, 4x4 frags. ONE barrier per K-step. XCD-chunked block swizzle:
// each XCD owns 4 row-panels x all 8 col-tiles (A+B ~4MB, L2-resident).
// ---------------------------------------------------------------------------
struct Stage { short8 h[2]; };

__device__ __forceinline__ void stage_load_f32(Stage& st, const float* Af, int row0, int K, int k0, int t) {
    const int row = t >> 1, half = t & 1;
    const float* p = Af + (size_t)(row0 + row) * K + k0 + half * 16;
    #pragma unroll
    for (int j = 0; j < 2; j++) {
        f4 v0 = *(const f4*)(p + j * 8);
        f4 v1 = *(const f4*)(p + j * 8 + 4);
        short8 hh;
        hh[0]=(short)f2bf(v0[0]); hh[1]=(short)f2bf(v0[1]); hh[2]=(short)f2bf(v0[2]); hh[3]=(short)f2bf(v0[3]);
        hh[4]=(short)f2bf(v1[0]); hh[5]=(short)f2bf(v1[1]); hh[6]=(short)f2bf(v1[2]); hh[7]=(short)f2bf(v1[3]);
        st.h[j] = hh;
    }
}

__device__ __forceinline__ void stage_store_f32(const Stage& st, u16* Ls, int t) {
    const int row = t >> 1, half = t & 1;
    #pragma unroll
    for (int j = 0; j < 2; j++) {
        int byteo = half * 32 + j * 16;
        *(short8*)((char*)Ls + row * 64 + (byteo ^ ((row & 3) << 4))) = st.h[j];
    }
}

template<int A_IS_F32, int OUT_IS_F32>
__global__ __launch_bounds__(256, 3)
void gemm_bt(const void* __restrict__ A0, const void* __restrict__ A1, const void* __restrict__ A2,
             const u16* __restrict__ Bt0, const u16* __restrict__ Bt1, const u16* __restrict__ Bt2,
             const float* __restrict__ bi0, const float* __restrict__ bi1, const float* __restrict__ bi2,
             void* __restrict__ C0, void* __restrict__ C1, void* __restrict__ C2,
             int M, int N, int K, float sc0, float sc1, float sc2)
{
    __shared__ __align__(16) u16 As[2][128 * 32];
    __shared__ __align__(16) u16 Bs[2][128 * 32];

    const int z = blockIdx.z;
    const void*  Aptr  = z == 0 ? A0  : z == 1 ? A1  : A2;
    const u16*   Bt    = z == 0 ? Bt0 : z == 1 ? Bt1 : Bt2;
    const float* bias  = z == 0 ? bi0 : z == 1 ? bi1 : bi2;
    void*        Cptr  = z == 0 ? C0  : z == 1 ? C1  : C2;
    const float  scale = z == 0 ? sc0 : z == 1 ? sc1 : sc2;

    const int t = threadIdx.x;
    const int w = t >> 6, l = t & 63, lr = l >> 4, lc = l & 15;
    const int wr = w >> 1, wc = w & 1;
    // XCD-chunked swizzle over the 8x32 (x,y) grid: xcd = dispatch%8 keeps
    // y in [xcd*4, xcd*4+4), x sweeping -> A panels + B stay in one L2.
    const int id = blockIdx.y * 8 + blockIdx.x;       // dispatch-linear (x fastest)
    const int xcd = id & 7, i_ = id >> 3;
    const int row0 = ((xcd << 2) | ((i_ >> 4) << 1) | ((i_ >> 3) & 1)) * 128;
    const int col0 = (i_ & 7) * 128;
    const int NI = K >> 5;

    // DMA a [128 rows][32 k] bf16 tile (rows of 64B = 4 chunks, pre-swizzled ^(row&3))
    auto issueT = [&](const u16* P, int r0_, int i, u16* dst) {
        #pragma unroll
        for (int j = 0; j < 2; j++) {
            int off = j * 256 + t;                  // 16B unit
            int row = off >> 2, ch = off & 3;
            const char* src = (const char*)P + (((size_t)(r0_ + row) * K + i * 32) << 1)
                              + ((ch ^ (row & 3)) << 4);
            gload16(src, (char*)dst + off * 16);
        }
    };

    f32x4 acc[4][4] = {};
    Stage sa;
    issueT(Bt, col0, 0, Bs[0]);
    if constexpr (A_IS_F32) {
        stage_load_f32(sa, (const float*)Aptr, row0, K, 0, t);
        stage_store_f32(sa, As[0], t);
        stage_load_f32(sa, (const float*)Aptr, row0, K, 32, t);
    } else {
        issueT((const u16*)Aptr, row0, 0, As[0]);
    }
    __syncthreads();

    for (int i = 0; i < NI; i++) {
        const int p = i & 1;
        if (i + 1 < NI) {
            issueT(Bt, col0, i + 1, Bs[p ^ 1]);
            if constexpr (A_IS_F32) {
                stage_store_f32(sa, As[p ^ 1], t);
                const int kn = (i + 2 < NI) ? (i + 2) * 32 : 0;
                stage_load_f32(sa, (const float*)Aptr, row0, K, kn, t);
            } else {
                issueT((const u16*)Aptr, row0, i + 1, As[p ^ 1]);
            }
        }

        short8 af[4], bf_[4];
        #pragma unroll
        for (int mm = 0; mm < 4; mm++) {
            int r = wr * 64 + mm * 16 + lc;
            af[mm] = *(const short8*)((const char*)As[p] + r * 64 + ((lr * 16) ^ ((r & 3) << 4)));
        }
        #pragma unroll
        for (int nn = 0; nn < 4; nn++) {
            int r = wc * 64 + nn * 16 + lc;
            bf_[nn] = *(const short8*)((const char*)Bs[p] + r * 64 + ((lr * 16) ^ ((r & 3) << 4)));
        }
        #pragma unroll
        for (int mm = 0; mm < 4; mm++)
            #pragma unroll
            for (int nn = 0; nn < 4; nn++)
                acc[mm][nn] = __builtin_amdgcn_mfma_f32_16x16x32_bf16(af[mm], bf_[nn], acc[mm][nn], 0, 0, 0);
        __syncthreads();
    }

    float bv[4];
    #pragma unroll
    for (int nn = 0; nn < 4; nn++) bv[nn] = bias[col0 + wc * 64 + nn * 16 + lc];

    #pragma unroll
    for (int mm = 0; mm < 4; mm++) {
        const int row = row0 + wr * 64 + mm * 16 + lr * 4;
        #pragma unroll
        for (int nn = 0; nn < 4; nn++) {
            const int col = col0 + wc * 64 + nn * 16 + lc;
            #pragma unroll
            for (int r = 0; r < 4; r++) {
                float vv = (acc[mm][nn][r] + bv[nn]) * scale;
                if constexpr (OUT_IS_F32) ((float*)Cptr)[(size_t)(row + r) * N + col] = vv;
                else                      ((u16*) Cptr)[(size_t)(row + r) * N + col] = f2bf(vv);
            }
        }
    }
}

// ---------------------------------------------------------------------------
// Fused attention, swapped QK^T (P in registers). Block = 128 q-rows x (b,h),
// 8 waves x 16 q-rows, KVBLK = 128. Double-buffered K/V via global_load_lds
// (pre-swizzled source), ONE barrier per tile. Pout via nontemporal stores.
// LDS = 80KB -> exactly 2 blocks/CU. XCD swizzle: 4 bh per XCD (K/V ~2MB L2).
// ---------------------------------------------------------------------------
__global__ __launch_bounds__(512, 4)
void attn_kernel(const u16* __restrict__ qp, const u16* __restrict__ kp,
                 const u16* __restrict__ vt, float* __restrict__ Pout,
                 u16* __restrict__ xout)
{
    __shared__ __align__(16) u16 Qs[128 * 64];      // 16KB [q][d], swizzled rows 128B
    __shared__ __align__(16) u16 Ks[2][128 * 64];   // 32KB [k][d], source-swizzled
    __shared__ __align__(16) u16 Vts[2][64 * 128];  // 32KB [d][k] rows 256B, source-swizzled

    const int t = threadIdx.x;
    const int w = t >> 6, l = t & 63, lr = l >> 4, lc = l & 15;
    // XCD-bijective swizzle: 512 blocks -> 8 chunks of 64 (= 4 bh each)
    const int bid = blockIdx.x;
    const int s = ((bid & 7) << 6) | (bid >> 3);
    const int q0 = (s & 15) * 128;
    const int bh = s >> 4, b = bh >> 4, h = bh & 15;
    const float L2E = 1.4426950408889634f;
    constexpr int NT = S_ / 128;                    // 16 tiles

    auto issueK = [&](int kt, int buf) {
        #pragma unroll
        for (int i = 0; i < 2; i++) {
            int off = i * 512 + t, row = off >> 3, ch = off & 7;
            const char* src = (const char*)kp + ((((size_t)b * S_ + kt * 128 + row) * D_ + h * 64) << 1)
                              + ((ch ^ (row & 7)) << 4);
            gload16(src, (char*)Ks[buf] + off * 16);
        }
    };
    auto issueV = [&](int kt, int buf) {
        #pragma unroll
        for (int i = 0; i < 2; i++) {
            int off = i * 512 + t, row = off >> 4, ch = off & 15;
            const char* src = (const char*)vt + ((((size_t)bh * 64 + row) * S_ + kt * 128) << 1)
                              + ((ch ^ (row & 7)) << 4);
            gload16(src, (char*)Vts[buf] + off * 16);
        }
    };

    issueK(0, 0);
    // stage Q tile [128 q][64 d] (reg-staged, swizzled)
    #pragma unroll
    for (int i = 0; i < 2; i++) {
        int c = t + 512 * i, row = c >> 3, ch = c & 7;
        short8 vq = *(const short8*)(qp + ((size_t)b * S_ + q0 + row) * D_ + h * 64 + ch * 8);
        *(short8*)((char*)Qs + row * 128 + ((ch * 16) ^ ((row & 7) << 4))) = vq;
    }
    __syncthreads();

    short8 qf[2];
    {
        int r = w * 16 + lc, sw = (r & 7) << 4;
        const char* qb = (const char*)Qs + r * 128;
        qf[0] = *(const short8*)(qb + ((lr * 16) ^ sw));
        qf[1] = *(const short8*)(qb + ((64 + lr * 16) ^ sw));
    }

    // ---------------- pass 1: per-lane sum of exp(s) over own k-slice ----------------
    float sum = 0.f;
    for (int kt = 0; kt < NT; kt++) {
        const int p = kt & 1;
        if (kt + 1 < NT) issueK(kt + 1, p ^ 1);
        const char* Kb = (const char*)Ks[p];
        #pragma unroll
        for (int f = 0; f < 8; f++) {
            int r = f * 16 + lc, sw = (r & 7) << 4;
            const char* kb = Kb + r * 128;
            short8 k0 = *(const short8*)(kb + ((lr * 16) ^ sw));
            short8 k1 = *(const short8*)(kb + ((64 + lr * 16) ^ sw));
            f32x4 sacc = {};
            sacc = __builtin_amdgcn_mfma_f32_16x16x32_bf16(k0, qf[0], sacc, 0, 0, 0);
            sacc = __builtin_amdgcn_mfma_f32_16x16x32_bf16(k1, qf[1], sacc, 0, 0, 0);
            sum += exp2f(sacc[0] * L2E) + exp2f(sacc[1] * L2E)
                 + exp2f(sacc[2] * L2E) + exp2f(sacc[3] * L2E);
        }
        __syncthreads();
    }
    issueK(0, 0); issueV(0, 0);                     // prefetch pass-2 tile 0 under the reduce
    sum += __shfl_xor(sum, 16);
    sum += __shfl_xor(sum, 32);
    const float inv = 1.0f / sum;
    __syncthreads();

    // ---------------- pass 2: P (regs) -> Pout dwordx4(nt) + in-register PV ----------------
    f32x4 xacc[4] = {};
    float* pbase = Pout + ((size_t)bh * S_ + q0 + w * 16 + lc) * S_ + lr * 4;

    for (int kt = 0; kt < NT; kt++) {
        const int p = kt & 1;
        if (kt + 1 < NT) { issueK(kt + 1, p ^ 1); issueV(kt + 1, p ^ 1); }
        const char* Kb = (const char*)Ks[p];
        const char* Vb = (const char*)Vts[p];

        #pragma unroll
        for (int kk = 0; kk < 4; kk++) {
            union { unsigned u[4]; short8 s8; } pu;
            #pragma unroll
            for (int fo = 0; fo < 2; fo++) {
                const int f = kk * 2 + fo;
                int r = f * 16 + lc, sw = (r & 7) << 4;
                const char* kb = Kb + r * 128;
                short8 k0 = *(const short8*)(kb + ((lr * 16) ^ sw));
                short8 k1 = *(const short8*)(kb + ((64 + lr * 16) ^ sw));
                f32x4 sacc = {};
                sacc = __builtin_amdgcn_mfma_f32_16x16x32_bf16(k0, qf[0], sacc, 0, 0, 0);
                sacc = __builtin_amdgcn_mfma_f32_16x16x32_bf16(k1, qf[1], sacc, 0, 0, 0);
                f32x4 pv_;
                pv_[0] = exp2f(sacc[0] * L2E) * inv;
                pv_[1] = exp2f(sacc[1] * L2E) * inv;
                pv_[2] = exp2f(sacc[2] * L2E) * inv;
                pv_[3] = exp2f(sacc[3] * L2E) * inv;
                __builtin_nontemporal_store(pv_, (f32x4*)(pbase + (size_t)kt * 128 + f * 16));
                pu.u[fo * 2 + 0] = (unsigned)f2bf(pv_[0]) | ((unsigned)f2bf(pv_[1]) << 16);
                pu.u[fo * 2 + 1] = (unsigned)f2bf(pv_[2]) | ((unsigned)f2bf(pv_[3]) << 16);
            }
            const short8 pa = pu.s8;   // A-frag: P[q=lc][k = kk*32 + perm(lr,j)]
            #pragma unroll
            for (int n = 0; n < 4; n++) {
                int rr = n * 16 + lc, sw2 = (rr & 7) << 4;
                const char* vrow = Vb + rr * 256;
                union { bfx4 h[2]; short8 s8; } vu;
                vu.h[0] = *(const bfx4*)(vrow + ((kk * 64 + lr * 8) ^ sw2));
                vu.h[1] = *(const bfx4*)(vrow + ((kk * 64 + 32 + lr * 8) ^ sw2));
                xacc[n] = __builtin_amdgcn_mfma_f32_16x16x32_bf16(pa, vu.s8, xacc[n], 0, 0, 0);
            }
        }
        __syncthreads();
    }

    #pragma unroll
    for (int n = 0; n < 4; n++) {
        #pragma unroll
        for (int r = 0; r < 4; r++) {
            int row = q0 + w * 16 + lr * 4 + r;
            int col = h * 64 + n * 16 + lc;
            xout[((size_t)b * S_ + row) * D_ + col] = f2bf(xacc[n][r]);
        }
    }
}

// ---------------------------------------------------------------------------
extern "C" void kernel_launch(void* const* d_in, const int* in_sizes, int n_in,
                              void* d_out, int out_size, void* d_ws, size_t ws_size,
                              hipStream_t stream)
{
    const float* qin = (const float*)d_in[0];
    const float* kin = (const float*)d_in[1];
    const float* vin = (const float*)d_in[2];
    const float* Wq  = (const float*)d_in[3];
    const float* bq  = (const float*)d_in[4];
    const float* Wk  = (const float*)d_in[5];
    const float* bk  = (const float*)d_in[6];
    const float* Wv  = (const float*)d_in[7];
    const float* bv  = (const float*)d_in[8];
    const float* Wo  = (const float*)d_in[9];
    const float* bo  = (const float*)d_in[10];

    // ws layout (u16 elements): 4x Wt (1M each) | qp | kp | vp (4M each) | vt | x
    u16* base = (u16*)d_ws;
    u16* Wqt = base;
    u16* Wkt = base + 1048576;
    u16* Wvt = base + 2097152;
    u16* Wot = base + 3145728;
    u16* qpb = base + 4194304;
    u16* kpb = base + 8388608;
    u16* vpb = base + 12582912;
    u16* vtb = base + 16777216;
    u16* xb  = base + 20971520;   // total ~50MB

    float* out  = (float*)d_out;
    float* Pout = out + OUT_ELEMS;

    const int M = B_ * S_;  // 4096

    wtrans_kernel<<<dim3(16, 16, 4), 256, 0, stream>>>(Wq, Wk, Wv, Wo, Wqt, Wkt, Wvt, Wot);
    // batched q/k/v projection; qp scaled by 1/sqrt(DK) = 0.125
    gemm_bt<1, 0><<<dim3(8, 32, 3), 256, 0, stream>>>(
        qin, kin, vin, Wqt, Wkt, Wvt, bq, bk, bv, qpb, kpb, vpb, M, D_, D_, 0.125f, 1.0f, 1.0f);
    vtrans_kernel<<<dim3(32, 32), 256, 0, stream>>>(vpb, vtb);
    attn_kernel<<<512, 512, 0, stream>>>(qpb, kpb, vtb, Pout, xb);
    gemm_bt<0, 1><<<dim3(8, 32, 1), 256, 0, stream>>>(
        xb, xb, xb, Wot, Wot, Wot, bo, bo, bo, out, out, out, M, D_, D_, 1.0f, 1.0f, 1.0f);
}